// Round 7
// baseline (770.740 us; speedup 1.0000x reference)
//
#include <hip/hip_runtime.h>

typedef float v2f __attribute__((ext_vector_type(2)));
typedef float v4f __attribute__((ext_vector_type(4)));

#define T_STEPS 2048
#define BATCH   2
#define IDIM    40
#define HDIM    44
#define GDIM    176      // 4*H
#define ADIM    262144
#define EDIM    88       // 2*H
#define NEG_L   (-1.4426950408889634f)   // -log2(e)
#define NEG_2L  (-2.8853900817779268f)   // -2*log2(e)

// K1: xproj[t][b][gi] = scale(gi) * (b_ih[gi] + b_hh[gi] + x[t][b]·W_ih[gi])
// scale = -log2e for i,f,o rows; -2log2e for g rows (exp2-folded gates).
__global__ __launch_bounds__(192) void xproj_kernel(
    const float* __restrict__ x,      // [T][B][40]
    const float* __restrict__ W_ih,   // [176][40]
    const float* __restrict__ b_ih,   // [176]
    const float* __restrict__ b_hh,   // [176]
    float* __restrict__ xproj)        // [T][B][176]
{
    const int tb = blockIdx.x;        // t*B + b
    const int gi = threadIdx.x;
    __shared__ __align__(16) float xs[IDIM];
    if (threadIdx.x < IDIM) xs[threadIdx.x] = x[(size_t)tb * IDIM + threadIdx.x];
    __syncthreads();
    if (gi < GDIM) {
        const float* wr = W_ih + gi * IDIM;
        float a0 = 0.f, a1 = 0.f;
        #pragma unroll
        for (int i = 0; i < IDIM; i += 4) {
            float4 wv = *(const float4*)&wr[i];
            float4 xv = *(const float4*)&xs[i];
            a0 += wv.x * xv.x + wv.z * xv.z;
            a1 += wv.y * xv.y + wv.w * xv.w;
        }
        const float scale = (gi >= 2 * HDIM && gi < 3 * HDIM) ? NEG_2L : NEG_L;
        xproj[(size_t)tb * GDIM + gi] = scale * (a0 + a1 + b_ih[gi] + b_hh[gi]);
    }
}

// K2: serial LSTM, ONE WAVE per batch. Lane j owns h[j], c[j] and gate rows
// {j, 44+j, 88+j, 132+j} of W_hh (pre-scaled by -log2e / -2log2e) in regs.
// h broadcast via LDS. Gates: y = scaled dot; w = rcp(1+exp2(y));
// sigmoid = w, tanh = 2w-1. Dual 11-deep FMA chains per gate.
__global__ __launch_bounds__(64)
__attribute__((amdgpu_waves_per_eu(1, 1)))
void lstm_kernel(
    const float* __restrict__ xproj,  // [T][B][176] (pre-scaled)
    const float* __restrict__ h0,     // [1][B][44]
    const float* __restrict__ c0,     // [1][B][44]
    const float* __restrict__ W_hh,   // [176][44]
    const float* __restrict__ W_v,    // [1][128]
    const float* __restrict__ b_v,    // [1]
    float* __restrict__ base_out)     // [B]
{
    const int b = blockIdx.x;
    const int j = threadIdx.x;          // 0..63; lanes >= 44 are passengers
    const int jj = (j < HDIM) ? j : (HDIM - 1);   // clamped (no OOB)

    __shared__ __align__(16) float h_sh[64];      // 44 live + 20 pad (lanes 44-63 scribble)

    // Per-lane weight rows, pre-scaled once (4 x 44 = 176 floats, 88 v2f)
    v2f wi[22], wf[22], wg[22], wo[22];
    {
        const float* ri = W_hh + (size_t)jj * HDIM;
        const float* rf = W_hh + (size_t)(HDIM + jj) * HDIM;
        const float* rg = W_hh + (size_t)(2 * HDIM + jj) * HDIM;
        const float* ro = W_hh + (size_t)(3 * HDIM + jj) * HDIM;
        #pragma unroll
        for (int k = 0; k < 22; ++k) {
            wi[k] = ((const v2f*)ri)[k] * NEG_L;
            wf[k] = ((const v2f*)rf)[k] * NEG_L;
            wg[k] = ((const v2f*)rg)[k] * NEG_2L;
            wo[k] = ((const v2f*)ro)[k] * NEG_L;
        }
    }

    float c = c0[b * HDIM + jj];
    h_sh[j] = (j < HDIM) ? h0[b * HDIM + j] : 0.f;
    __syncthreads();

    // broadcast-read full h into registers (all lanes)
    v2f hp[22];
    #pragma unroll
    for (int k = 0; k < 11; ++k) {
        v4f t = ((const v4f*)h_sh)[k];
        hp[2 * k]     = __builtin_shufflevector(t, t, 0, 1);
        hp[2 * k + 1] = __builtin_shufflevector(t, t, 2, 3);
    }

    const float* xp = xproj + (size_t)b * GDIM;   // step stride = B*GDIM
    // 3-deep prefetch pipeline: r = step s, p = s+1, q = s+2
    #define LDX(dst, s) { const float* _a = xp + (size_t)(s) * (BATCH * GDIM); \
        dst##0 = _a[jj]; dst##1 = _a[HDIM + jj]; dst##2 = _a[2 * HDIM + jj]; dst##3 = _a[3 * HDIM + jj]; }
    float r0, r1, r2, r3, p0, p1, p2, p3, q0, q1, q2, q3;
    LDX(r, 0) LDX(p, 1) LDX(q, 2)

    float hval = 0.f;

    #pragma unroll 1
    for (int step = 0; step < T_STEPS; ++step) {
        // dual 11-deep packed accumulator chains per gate
        v2f ai0 = (v2f)(0.f), ai1 = (v2f)(0.f), af0 = (v2f)(0.f), af1 = (v2f)(0.f);
        v2f ag0 = (v2f)(0.f), ag1 = (v2f)(0.f), ao0 = (v2f)(0.f), ao1 = (v2f)(0.f);
        #pragma unroll
        for (int k = 0; k < 22; k += 2) {
            ai0 = __builtin_elementwise_fma(wi[k],     hp[k],     ai0);
            ai1 = __builtin_elementwise_fma(wi[k + 1], hp[k + 1], ai1);
            af0 = __builtin_elementwise_fma(wf[k],     hp[k],     af0);
            af1 = __builtin_elementwise_fma(wf[k + 1], hp[k + 1], af1);
            ag0 = __builtin_elementwise_fma(wg[k],     hp[k],     ag0);
            ag1 = __builtin_elementwise_fma(wg[k + 1], hp[k + 1], ag1);
            ao0 = __builtin_elementwise_fma(wo[k],     hp[k],     ao0);
            ao1 = __builtin_elementwise_fma(wo[k + 1], hp[k + 1], ao1);
        }
        v2f si2 = ai0 + ai1; float yi = si2.x + si2.y + r0;
        v2f sf2 = af0 + af1; float yf = sf2.x + sf2.y + r1;
        v2f sg2 = ag0 + ag1; float yg = sg2.x + sg2.y + r2;
        v2f so2 = ao0 + ao1; float yo = so2.x + so2.y + r3;

        // w = rcp(1+exp2(y)); sigmoid = w, tanh = 2w-1
        float s_i = __builtin_amdgcn_rcpf(1.0f + __builtin_amdgcn_exp2f(yi));
        float s_f = __builtin_amdgcn_rcpf(1.0f + __builtin_amdgcn_exp2f(yf));
        float w_g = __builtin_amdgcn_rcpf(1.0f + __builtin_amdgcn_exp2f(yg));
        float s_o = __builtin_amdgcn_rcpf(1.0f + __builtin_amdgcn_exp2f(yo));
        float t_g = __builtin_fmaf(2.0f, w_g, -1.0f);
        c = s_f * c + s_i * t_g;
        float y_c = c * NEG_2L;
        float w_c = __builtin_amdgcn_rcpf(1.0f + __builtin_amdgcn_exp2f(y_c));
        float two_so = s_o + s_o;
        hval = __builtin_fmaf(two_so, w_c, -s_o);   // s_o * tanh(c)

        h_sh[j] = hval;                              // unconditional (padded)
        __syncthreads();

        #pragma unroll
        for (int k = 0; k < 11; ++k) {
            v4f t = ((const v4f*)h_sh)[k];
            hp[2 * k]     = __builtin_shufflevector(t, t, 0, 1);
            hp[2 * k + 1] = __builtin_shufflevector(t, t, 2, 3);
        }

        // rotate prefetch pipeline; issue loads for step+3
        r0 = p0; r1 = p1; r2 = p2; r3 = p3;
        p0 = q0; p1 = q1; p2 = q2; p3 = q3;
        const int ns = (step + 3 < T_STEPS) ? step + 3 : (T_STEPS - 1);
        LDX(q, ns)
    }
    #undef LDX

    // epilogue: base[b] = sum_j h[j]*Wv[j] + c[j]*Wv[44+j] + b_v
    float p = 0.f;
    if (j < HDIM) p = hval * W_v[j] + c * W_v[HDIM + j];
    #pragma unroll
    for (int off = 32; off; off >>= 1) p += __shfl_down(p, off);
    if (j == 0) base_out[b] = p + b_v[0];
}

// K3: out[b][a] = (a < len[b]) ? base[b] + action[b][a][:].w_a : 0
__global__ __launch_bounds__(256) void action_kernel(
    const float* __restrict__ action,     // [B][A][40]
    const int*   __restrict__ act_length, // [B]
    const float* __restrict__ W_v,        // [1][128]; w_a = W_v[88..127]
    const float* __restrict__ base,       // [B]
    float* __restrict__ out)              // [B][A]
{
    const int idx = blockIdx.x * 256 + threadIdx.x;   // 0 .. B*A-1
    const int b = idx >> 18;                          // A = 2^18
    const int a = idx & (ADIM - 1);
    if (a >= act_length[b]) { out[idx] = 0.f; return; }
    const float* row = action + (size_t)idx * IDIM;
    float a0 = 0.f, a1 = 0.f;
    #pragma unroll
    for (int i = 0; i < IDIM; i += 4) {
        float4 av = *(const float4*)&row[i];
        a0 += av.x * W_v[EDIM + i + 0] + av.z * W_v[EDIM + i + 2];
        a1 += av.y * W_v[EDIM + i + 1] + av.w * W_v[EDIM + i + 3];
    }
    out[idx] = base[b] + a0 + a1;
}

extern "C" void kernel_launch(void* const* d_in, const int* in_sizes, int n_in,
                              void* d_out, int out_size, void* d_ws, size_t ws_size,
                              hipStream_t stream) {
    const float* x        = (const float*)d_in[0];
    const float* h0       = (const float*)d_in[1];
    const float* c0       = (const float*)d_in[2];
    const float* action   = (const float*)d_in[3];
    const int*   act_len  = (const int*)  d_in[4];
    const float* W_ih     = (const float*)d_in[5];
    const float* W_hh     = (const float*)d_in[6];
    const float* b_ih     = (const float*)d_in[7];
    const float* b_hh     = (const float*)d_in[8];
    const float* W_v      = (const float*)d_in[9];
    const float* b_v      = (const float*)d_in[10];
    float* out = (float*)d_out;

    float* xproj = (float*)d_ws;                                   // [T][B][176]
    float* base  = xproj + (size_t)T_STEPS * BATCH * GDIM;         // B floats

    xproj_kernel<<<dim3(T_STEPS * BATCH), dim3(192), 0, stream>>>(
        x, W_ih, b_ih, b_hh, xproj);
    lstm_kernel<<<dim3(BATCH), dim3(64), 0, stream>>>(
        xproj, h0, c0, W_hh, W_v, b_v, base);
    action_kernel<<<dim3((BATCH * ADIM) / 256), dim3(256), 0, stream>>>(
        action, act_len, W_v, base, out);
}

// Round 8
// 694.568 us; speedup vs baseline: 1.1097x; 1.1097x over previous
//
#include <hip/hip_runtime.h>

typedef float v2f __attribute__((ext_vector_type(2)));
typedef float v4f __attribute__((ext_vector_type(4)));

#define T_STEPS 2048
#define BATCH   2
#define IDIM    40
#define HDIM    44
#define GDIM    176      // 4*H
#define ADIM    262144
#define EDIM    88       // 2*H
#define NEG_L   (-1.4426950408889634f)   // -log2(e)
#define NEG_2L  (-2.8853900817779268f)   // -2*log2(e)

// K1: xproj[t][b][gi] = scale(gi) * (b_ih[gi] + b_hh[gi] + x[t][b]·W_ih[gi])
// scale = -log2e for i,f,o rows; -2log2e for g rows (exp2-folded gates).
__global__ __launch_bounds__(192) void xproj_kernel(
    const float* __restrict__ x,      // [T][B][40]
    const float* __restrict__ W_ih,   // [176][40]
    const float* __restrict__ b_ih,   // [176]
    const float* __restrict__ b_hh,   // [176]
    float* __restrict__ xproj)        // [T][B][176]
{
    const int tb = blockIdx.x;        // t*B + b
    const int gi = threadIdx.x;
    __shared__ __align__(16) float xs[IDIM];
    if (threadIdx.x < IDIM) xs[threadIdx.x] = x[(size_t)tb * IDIM + threadIdx.x];
    __syncthreads();
    if (gi < GDIM) {
        const float* wr = W_ih + gi * IDIM;
        float a0 = 0.f, a1 = 0.f;
        #pragma unroll
        for (int i = 0; i < IDIM; i += 4) {
            float4 wv = *(const float4*)&wr[i];
            float4 xv = *(const float4*)&xs[i];
            a0 += wv.x * xv.x + wv.z * xv.z;
            a1 += wv.y * xv.y + wv.w * xv.w;
        }
        const float scale = (gi >= 2 * HDIM && gi < 3 * HDIM) ? NEG_2L : NEG_L;
        xproj[(size_t)tb * GDIM + gi] = scale * (a0 + a1 + b_ih[gi] + b_hh[gi]);
    }
}

// K2: serial LSTM, ONE WAVE per batch. Lane j owns h[j], c[j] and gate rows
// {j, 44+j, 88+j, 132+j} of W_hh (pre-scaled) in regs. h broadcast via LDS
// WITHOUT any barrier: a single wave's DS ops execute in order, so the
// ds_read after ds_write of h_sh needs no write-drain and no s_barrier —
// the only wait is the read-data lgkmcnt the compiler inserts anyway.
// (r4/r5/r6 showed the ~840cyc step is a fixed serial cost; the write-drain
// + s_barrier pair was the largest untested chunk, ~150-250 cyc.)
__global__ __launch_bounds__(64)
__attribute__((amdgpu_waves_per_eu(1, 1)))
void lstm_kernel(
    const float* __restrict__ xproj,  // [T][B][176] (pre-scaled)
    const float* __restrict__ h0,     // [1][B][44]
    const float* __restrict__ c0,     // [1][B][44]
    const float* __restrict__ W_hh,   // [176][44]
    const float* __restrict__ W_v,    // [1][128]
    const float* __restrict__ b_v,    // [1]
    float* __restrict__ base_out)     // [B]
{
    const int b = blockIdx.x;
    const int j = threadIdx.x;          // 0..63; lanes >= 44 are passengers
    const int jj = (j < HDIM) ? j : (HDIM - 1);   // clamped (no OOB)

    __shared__ __align__(16) float h_sh[64];      // 44 live + pad; all 64 lanes write

    // Per-lane weight rows, pre-scaled once (4 x 44 = 176 floats, 88 v2f)
    v2f wi[22], wf[22], wg[22], wo[22];
    {
        const float* ri = W_hh + (size_t)jj * HDIM;
        const float* rf = W_hh + (size_t)(HDIM + jj) * HDIM;
        const float* rg = W_hh + (size_t)(2 * HDIM + jj) * HDIM;
        const float* ro = W_hh + (size_t)(3 * HDIM + jj) * HDIM;
        #pragma unroll
        for (int k = 0; k < 22; ++k) {
            wi[k] = ((const v2f*)ri)[k] * NEG_L;
            wf[k] = ((const v2f*)rf)[k] * NEG_L;
            wg[k] = ((const v2f*)rg)[k] * NEG_2L;
            wo[k] = ((const v2f*)ro)[k] * NEG_L;
        }
    }

    float c = c0[b * HDIM + jj];
    h_sh[j] = (j < HDIM) ? h0[b * HDIM + j] : 0.f;   // same-wave in-order DS

    // broadcast-read full h into registers (all lanes)
    v2f hp[22];
    #pragma unroll
    for (int k = 0; k < 11; ++k) {
        v4f t = ((const v4f*)h_sh)[k];
        hp[2 * k]     = __builtin_shufflevector(t, t, 0, 1);
        hp[2 * k + 1] = __builtin_shufflevector(t, t, 2, 3);
    }

    const float* xp = xproj + (size_t)b * GDIM;   // step stride = B*GDIM
    #define LDX(dst, s) { const float* _a = xp + (size_t)(s) * (BATCH * GDIM); \
        dst##0 = _a[jj]; dst##1 = _a[HDIM + jj]; dst##2 = _a[2 * HDIM + jj]; dst##3 = _a[3 * HDIM + jj]; }
    float r0, r1, r2, r3, p0, p1, p2, p3;
    LDX(r, 0) LDX(p, 1)

    float hval = 0.f;

    #pragma unroll 1
    for (int step = 0; step < T_STEPS; ++step) {
        // dual 11-deep packed accumulator chains per gate
        v2f ai0 = (v2f)(0.f), ai1 = (v2f)(0.f), af0 = (v2f)(0.f), af1 = (v2f)(0.f);
        v2f ag0 = (v2f)(0.f), ag1 = (v2f)(0.f), ao0 = (v2f)(0.f), ao1 = (v2f)(0.f);
        #pragma unroll
        for (int k = 0; k < 22; k += 2) {
            ai0 = __builtin_elementwise_fma(wi[k],     hp[k],     ai0);
            ai1 = __builtin_elementwise_fma(wi[k + 1], hp[k + 1], ai1);
            af0 = __builtin_elementwise_fma(wf[k],     hp[k],     af0);
            af1 = __builtin_elementwise_fma(wf[k + 1], hp[k + 1], af1);
            ag0 = __builtin_elementwise_fma(wg[k],     hp[k],     ag0);
            ag1 = __builtin_elementwise_fma(wg[k + 1], hp[k + 1], ag1);
            ao0 = __builtin_elementwise_fma(wo[k],     hp[k],     ao0);
            ao1 = __builtin_elementwise_fma(wo[k + 1], hp[k + 1], ao1);
        }
        v2f si2 = ai0 + ai1; float yi = si2.x + si2.y + r0;
        v2f sf2 = af0 + af1; float yf = sf2.x + sf2.y + r1;
        v2f sg2 = ag0 + ag1; float yg = sg2.x + sg2.y + r2;
        v2f so2 = ao0 + ao1; float yo = so2.x + so2.y + r3;

        // w = rcp(1+exp2(y)); sigmoid = w, tanh = 2w-1
        float s_i = __builtin_amdgcn_rcpf(1.0f + __builtin_amdgcn_exp2f(yi));
        float s_f = __builtin_amdgcn_rcpf(1.0f + __builtin_amdgcn_exp2f(yf));
        float w_g = __builtin_amdgcn_rcpf(1.0f + __builtin_amdgcn_exp2f(yg));
        float s_o = __builtin_amdgcn_rcpf(1.0f + __builtin_amdgcn_exp2f(yo));
        float t_g = __builtin_fmaf(2.0f, w_g, -1.0f);
        c = s_f * c + s_i * t_g;
        float y_c = c * NEG_2L;
        float w_c = __builtin_amdgcn_rcpf(1.0f + __builtin_amdgcn_exp2f(y_c));
        float two_so = s_o + s_o;
        hval = __builtin_fmaf(two_so, w_c, -s_o);   // s_o * tanh(c)

        // h broadcast: write then read, same wave, in-order DS pipe — NO barrier
        h_sh[j] = hval;
        #pragma unroll
        for (int k = 0; k < 11; ++k) {
            v4f t = ((const v4f*)h_sh)[k];
            hp[2 * k]     = __builtin_shufflevector(t, t, 0, 1);
            hp[2 * k + 1] = __builtin_shufflevector(t, t, 2, 3);
        }

        // rotate prefetch (2-deep, as in round 4)
        r0 = p0; r1 = p1; r2 = p2; r3 = p3;
        const int ns = (step + 2 < T_STEPS) ? step + 2 : (T_STEPS - 1);
        LDX(p, ns)
    }
    #undef LDX

    // epilogue: base[b] = sum_j h[j]*Wv[j] + c[j]*Wv[44+j] + b_v
    float p = 0.f;
    if (j < HDIM) p = hval * W_v[j] + c * W_v[HDIM + j];
    #pragma unroll
    for (int off = 32; off; off >>= 1) p += __shfl_down(p, off);
    if (j == 0) base_out[b] = p + b_v[0];
}

// K3: out[b][a] = (a < len[b]) ? base[b] + action[b][a][:].w_a : 0
__global__ __launch_bounds__(256) void action_kernel(
    const float* __restrict__ action,     // [B][A][40]
    const int*   __restrict__ act_length, // [B]
    const float* __restrict__ W_v,        // [1][128]; w_a = W_v[88..127]
    const float* __restrict__ base,       // [B]
    float* __restrict__ out)              // [B][A]
{
    const int idx = blockIdx.x * 256 + threadIdx.x;   // 0 .. B*A-1
    const int b = idx >> 18;                          // A = 2^18
    const int a = idx & (ADIM - 1);
    if (a >= act_length[b]) { out[idx] = 0.f; return; }
    const float* row = action + (size_t)idx * IDIM;
    float a0 = 0.f, a1 = 0.f;
    #pragma unroll
    for (int i = 0; i < IDIM; i += 4) {
        float4 av = *(const float4*)&row[i];
        a0 += av.x * W_v[EDIM + i + 0] + av.z * W_v[EDIM + i + 2];
        a1 += av.y * W_v[EDIM + i + 1] + av.w * W_v[EDIM + i + 3];
    }
    out[idx] = base[b] + a0 + a1;
}

extern "C" void kernel_launch(void* const* d_in, const int* in_sizes, int n_in,
                              void* d_out, int out_size, void* d_ws, size_t ws_size,
                              hipStream_t stream) {
    const float* x        = (const float*)d_in[0];
    const float* h0       = (const float*)d_in[1];
    const float* c0       = (const float*)d_in[2];
    const float* action   = (const float*)d_in[3];
    const int*   act_len  = (const int*)  d_in[4];
    const float* W_ih     = (const float*)d_in[5];
    const float* W_hh     = (const float*)d_in[6];
    const float* b_ih     = (const float*)d_in[7];
    const float* b_hh     = (const float*)d_in[8];
    const float* W_v      = (const float*)d_in[9];
    const float* b_v      = (const float*)d_in[10];
    float* out = (float*)d_out;

    float* xproj = (float*)d_ws;                                   // [T][B][176]
    float* base  = xproj + (size_t)T_STEPS * BATCH * GDIM;         // B floats

    xproj_kernel<<<dim3(T_STEPS * BATCH), dim3(192), 0, stream>>>(
        x, W_ih, b_ih, b_hh, xproj);
    lstm_kernel<<<dim3(BATCH), dim3(64), 0, stream>>>(
        xproj, h0, c0, W_hh, W_v, b_v, base);
    action_kernel<<<dim3((BATCH * ADIM) / 256), dim3(256), 0, stream>>>(
        action, act_len, W_v, base, out);
}